// Round 5
// baseline (197.348 us; speedup 1.0000x reference)
//
#include <hip/hip_runtime.h>
#include <hip/hip_cooperative_groups.h>
#include <math.h>

namespace cg = cooperative_groups;

// L = diag((W+W^T).sum(1)) - (W+W^T), cotangent weights per face.
// Single cooperative kernel: phase 1 zeroes the 256MB output at streaming
// rate (pure float4 stores, grid-stride), grid.sync(), phase 2 scatters the
// ~196K atomic contributions (16 faces/block, fire-and-forget atomics).
// This removes R1's separate scatter-kernel node + inter-node gap (~13us).

#define NB 1024
#define NT 256

typedef float v4f __attribute__((ext_vector_type(4)));

__device__ __forceinline__ void cot_weights(const float* __restrict__ V,
                                            int i0, int i1, int i2,
                                            float& c0, float& c1, float& c2) {
    const float ax = V[i0 * 3 + 0], ay = V[i0 * 3 + 1], az = V[i0 * 3 + 2];
    const float bx = V[i1 * 3 + 0], by = V[i1 * 3 + 1], bz = V[i1 * 3 + 2];
    const float cx = V[i2 * 3 + 0], cy = V[i2 * 3 + 1], cz = V[i2 * 3 + 2];

    float dx, dy, dz, d2;
    dx = bx - cx; dy = by - cy; dz = bz - cz;
    d2 = dx * dx + dy * dy + dz * dz;
    const float l1 = (d2 > 0.0f) ? sqrtf(d2) : 0.0f;
    dx = cx - ax; dy = cy - ay; dz = cz - az;
    d2 = dx * dx + dy * dy + dz * dz;
    const float l2 = (d2 > 0.0f) ? sqrtf(d2) : 0.0f;
    dx = ax - bx; dy = ay - by; dz = az - bz;
    d2 = dx * dx + dy * dy + dz * dz;
    const float l3 = (d2 > 0.0f) ? sqrtf(d2) : 0.0f;

    const float sp = (l1 + l2 + l3) * 0.5f;
    const float s  = sp * (sp - l1) * (sp - l2) * (sp - l3);
    const float A  = (s > 0.0f) ? 2.0f * sqrtf(s) : 1.0f;

    c0 = ((l2 * l2 + l3 * l3 - l1 * l1) / A) * 0.25f; // (r=i1, c=i2)
    c1 = ((l1 * l1 + l3 * l3 - l2 * l2) / A) * 0.25f; // (r=i2, c=i0)
    c2 = ((l1 * l1 + l2 * l2 - l3 * l3) / A) * 0.25f; // (r=i0, c=i1)
}

__device__ __forceinline__ void scatter_face(const float* __restrict__ V,
                                             const int* __restrict__ Fw,
                                             float* __restrict__ L,
                                             int f, bool is64, size_t n) {
    int i0, i1, i2;
    if (is64) { i0 = Fw[f * 6]; i1 = Fw[f * 6 + 2]; i2 = Fw[f * 6 + 4]; }
    else      { i0 = Fw[f * 3]; i1 = Fw[f * 3 + 1]; i2 = Fw[f * 3 + 2]; }

    float c0, c1, c2;
    cot_weights(V, i0, i1, i2, c0, c1, c2);

    const int rr_[3] = {i1, i2, i0};
    const int cc_[3] = {i2, i0, i1};
    const float vv_[3] = {c0, c1, c2};
#pragma unroll
    for (int t = 0; t < 3; ++t) {
        const int r = rr_[t], c = cc_[t];
        const float v = vv_[t];
        atomicAdd(&L[(size_t)r * n + c], -v);
        atomicAdd(&L[(size_t)c * n + r], -v);
        atomicAdd(&L[(size_t)r * n + r],  v);
        atomicAdd(&L[(size_t)c * n + c],  v);
    }
}

__global__ __launch_bounds__(NT, 4) void fused_zero_scatter_kernel(
        const float* __restrict__ V, const int* __restrict__ Fw,
        float* __restrict__ L, int nF, int N) {
    const int tid = threadIdx.x;
    const int bid = blockIdx.x;
    const size_t gid = (size_t)bid * NT + tid;

    // ---- phase 1: zero the output (coalesced float4 grid-stride) ----
    const size_t total4 = ((size_t)N * (size_t)N) >> 2;
    v4f* out4 = (v4f*)L;
    for (size_t j = gid; j < total4; j += (size_t)NB * NT)
        out4[j] = (v4f)0.0f;

    cg::this_grid().sync();   // device-scope fence: zeros visible everywhere

    // ---- phase 2: scatter (16 faces per block, threads 0..15) ----
    const int fpb = (nF + NB - 1) / NB;
    if (tid < fpb) {
        const int f = bid * fpb + tid;
        if (f < nF) {
            const bool is64 = (Fw[1] == 0) && (Fw[3] == 0) && (Fw[5] == 0) &&
                              (Fw[7] == 0) && (Fw[9] == 0) && (Fw[11] == 0);
            scatter_face(V, Fw, L, f, is64, (size_t)N);
        }
    }
}

// ---- fallback (N % 4 != 0 or cooperative limits): memset + scatter ----
__global__ void face_scatter_kernel(const float* __restrict__ V, const int* __restrict__ Fw,
                                    float* __restrict__ L, int nF, int N) {
    int f = blockIdx.x * blockDim.x + threadIdx.x;
    if (f >= nF) return;
    const bool is64 = (Fw[1] == 0) && (Fw[3] == 0) && (Fw[5] == 0) &&
                      (Fw[7] == 0) && (Fw[9] == 0) && (Fw[11] == 0);
    scatter_face(V, Fw, L, f, is64, (size_t)N);
}

extern "C" void kernel_launch(void* const* d_in, const int* in_sizes, int n_in,
                              void* d_out, int out_size, void* d_ws, size_t ws_size,
                              hipStream_t stream) {
    const float* V = (const float*)d_in[0];
    const int* Fw  = (const int*)d_in[1];
    float* L       = (float*)d_out;

    int N  = in_sizes[0] / 3;   // 8192 vertices
    int nF = in_sizes[1] / 3;   // 16384 faces

    if ((N & 3) == 0 && (size_t)N * N >= (size_t)NB * NT * 4) {
        void* args[] = {(void*)&V, (void*)&Fw, (void*)&L, (void*)&nF, (void*)&N};
        hipLaunchCooperativeKernel((void*)fused_zero_scatter_kernel,
                                   dim3(NB), dim3(NT), args, 0, stream);
    } else {
        hipMemsetAsync(d_out, 0, (size_t)out_size * sizeof(float), stream);
        const int block = 256;
        face_scatter_kernel<<<(nF + block - 1) / block, block, 0, stream>>>(V, Fw, L, nF, N);
    }
}

// Round 6
// 50.728 us; speedup vs baseline: 3.8903x; 3.8903x over previous
//
#include <hip/hip_runtime.h>
#include <math.h>

// L = diag((W+W^T).sum(1)) - (W+W^T), cotangent weights per face.
// Structure (best measured): node 1 = hipMemsetAsync of the 256MB output
// (rocclr fill runs at ~7 TB/s = the structural floor), node 2 = scatter.
// Scatter is one CORNER per thread (3 threads/face): 4 atomics/thread,
// 3x the wave parallelism of face-per-thread, ~3us instead of ~12us.

typedef float v4f __attribute__((ext_vector_type(4)));

__global__ __launch_bounds__(256) void corner_scatter_kernel(
        const float* __restrict__ V, const int* __restrict__ Fw,
        float* __restrict__ L, int nF, int N) {
    const int g = blockIdx.x * 256 + threadIdx.x;
    const int total = nF * 3;
    if (g >= total) return;

    const int f = g / 3;           // compiler emits magic-mul
    const int t = g - f * 3;       // corner 0/1/2

    // int64 vs int32 layout detection (little-endian high words all zero;
    // broadcast loads, L1-hot)
    const bool is64 = (Fw[1] == 0) && (Fw[3] == 0) && (Fw[5] == 0) &&
                      (Fw[7] == 0) && (Fw[9] == 0) && (Fw[11] == 0);

    int i0, i1, i2;
    if (is64) { i0 = Fw[f * 6]; i1 = Fw[f * 6 + 2]; i2 = Fw[f * 6 + 4]; }
    else      { i0 = Fw[f * 3]; i1 = Fw[f * 3 + 1]; i2 = Fw[f * 3 + 2]; }

    // v1 = V[i0], v2 = V[i1], v3 = V[i2]  (V is 96KB -> L1/L2-hot)
    const float ax = V[i0 * 3 + 0], ay = V[i0 * 3 + 1], az = V[i0 * 3 + 2];
    const float bx = V[i1 * 3 + 0], by = V[i1 * 3 + 1], bz = V[i1 * 3 + 2];
    const float cx = V[i2 * 3 + 0], cy = V[i2 * 3 + 1], cz = V[i2 * 3 + 2];

    float dx, dy, dz, d2;
    dx = bx - cx; dy = by - cy; dz = bz - cz;
    d2 = dx * dx + dy * dy + dz * dz;
    const float l1 = (d2 > 0.0f) ? sqrtf(d2) : 0.0f;
    dx = cx - ax; dy = cy - ay; dz = cz - az;
    d2 = dx * dx + dy * dy + dz * dz;
    const float l2 = (d2 > 0.0f) ? sqrtf(d2) : 0.0f;
    dx = ax - bx; dy = ay - by; dz = az - bz;
    d2 = dx * dx + dy * dy + dz * dz;
    const float l3 = (d2 > 0.0f) ? sqrtf(d2) : 0.0f;

    const float sp = (l1 + l2 + l3) * 0.5f;
    const float s  = sp * (sp - l1) * (sp - l2) * (sp - l3);
    const float A  = (s > 0.0f) ? 2.0f * sqrtf(s) : 1.0f;

    const float q1 = l1 * l1, q2 = l2 * l2, q3 = l3 * l3;
    // corner t: numerator + (row, col) selection
    const float num = (t == 0) ? (q2 + q3 - q1)
                    : (t == 1) ? (q1 + q3 - q2)
                               : (q1 + q2 - q3);
    const int r = (t == 0) ? i1 : (t == 1) ? i2 : i0;
    const int c = (t == 0) ? i2 : (t == 1) ? i0 : i1;
    const float v = (num / A) * 0.25f;

    const size_t n = (size_t)N;
    atomicAdd(&L[(size_t)r * n + c], -v);
    atomicAdd(&L[(size_t)c * n + r], -v);
    atomicAdd(&L[(size_t)r * n + r],  v);
    atomicAdd(&L[(size_t)c * n + c],  v);
}

extern "C" void kernel_launch(void* const* d_in, const int* in_sizes, int n_in,
                              void* d_out, int out_size, void* d_ws, size_t ws_size,
                              hipStream_t stream) {
    const float* V = (const float*)d_in[0];
    const int* Fw  = (const int*)d_in[1];
    float* L       = (float*)d_out;

    const int N  = in_sizes[0] / 3;   // 8192 vertices
    const int nF = in_sizes[1] / 3;   // 16384 faces

    // Node 1: zero the output at fill rate (~7 TB/s, the structural floor)
    hipMemsetAsync(d_out, 0, (size_t)out_size * sizeof(float), stream);

    // Node 2: corner-per-thread scatter (3*nF threads, 4 atomics each)
    const int total = nF * 3;
    const int block = 256;
    corner_scatter_kernel<<<(total + block - 1) / block, block, 0, stream>>>(
        V, Fw, L, nF, N);
}